// Round 4
// baseline (541.665 us; speedup 1.0000x reference)
//
#include <hip/hip_runtime.h>
#include <hip/hip_bf16.h>
#include <math.h>

// Problem constants (from reference)
constexpr int Bb   = 32;
constexpr int Ls   = 110;
constexpr int Gs   = 512;
constexpr int Ns   = 40;
constexpr int Ds   = 300;
constexpr int WPc  = 10;
constexpr int WFc  = 10;
constexpr int MAXNc = 110;
constexpr float EPSf  = 1e-8f;
constexpr float CLIPf = 1.0f - 1e-6f;
constexpr int BL = Bb * Ls;        // 3520
constexpr int Mrows = BL * Ns;     // 140800 flattened GEMM rows

typedef __attribute__((ext_vector_type(8))) short short8_t;
typedef __attribute__((ext_vector_type(4))) short short4_t;
typedef __attribute__((ext_vector_type(4))) float floatx4;

__device__ __forceinline__ unsigned short bf16r(float f) {
  unsigned u = __float_as_uint(f);
  u += 0x7fffu + ((u >> 16) & 1u);          // RNE to bf16
  return (unsigned short)(u >> 16);
}

// pack two f32 -> one VGPR holding 2 bf16 (RNE), low = lo
__device__ __forceinline__ unsigned pkbf(float lo, float hi) {
  unsigned a = __float_as_uint(lo), b = __float_as_uint(hi);
  a += 0x7fffu + ((a >> 16) & 1u);
  b += 0x7fffu + ((b >> 16) & 1u);
  return (a >> 16) | (b & 0xffff0000u);
}

__device__ __forceinline__ short8_t cvt8(const float4 v0, const float4 v1) {
  union { short8_t s; unsigned u[4]; } p;
  p.u[0] = pkbf(v0.x, v0.y);
  p.u[1] = pkbf(v0.z, v0.w);
  p.u[2] = pkbf(v1.x, v1.y);
  p.u[3] = pkbf(v1.z, v1.w);
  return p.s;
}

// ---------------------------------------------------------------------------
// Kernel 0: transpose W_sem (512x512) so the sem GEMM reads it coalesced.
// ---------------------------------------------------------------------------
__global__ __launch_bounds__(256) void transpose_wsem(const float* __restrict__ w,
                                                      float* __restrict__ wt) {
  __shared__ float tile[32][33];
  const int bx = blockIdx.x * 32;
  const int by = blockIdx.y * 32;
  const int tx = threadIdx.x;   // 0..31
  const int ty = threadIdx.y;   // 0..7
#pragma unroll
  for (int r = ty; r < 32; r += 8)
    tile[r][tx] = w[(by + r) * Gs + (bx + tx)];
  __syncthreads();
#pragma unroll
  for (int r = ty; r < 32; r += 8)
    wt[(bx + r) * Gs + (by + tx)] = tile[tx][r];   // wt[t][s] = w[s][t]
}

// ---------------------------------------------------------------------------
// Kernel 0b: WcT[t][s] = bf16(Wc[s][t]), zero-padded to [320][320].
// ---------------------------------------------------------------------------
__global__ __launch_bounds__(256) void wct_prep(const float* __restrict__ wc,
                                                short* __restrict__ wct) {
  __shared__ float tile[32][33];
  const int t0 = blockIdx.x * 32;   // t tile
  const int s0 = blockIdx.y * 32;   // s tile
  const int tx = threadIdx.x, ty = threadIdx.y;
#pragma unroll
  for (int r = ty; r < 32; r += 8) {
    const int s = s0 + r, t = t0 + tx;
    tile[r][tx] = (s < Ds && t < Ds) ? wc[s * Ds + t] : 0.f;
  }
  __syncthreads();
#pragma unroll
  for (int r = ty; r < 32; r += 8) {
    const int t = t0 + r, s = s0 + tx;
    wct[t * 320 + s] = (short)bf16r(tile[tx][r]);
  }
}

// ---------------------------------------------------------------------------
// Kernel 1: att_sem[bl,s] = sum_t W[s,t] * x[bl,t]
// ---------------------------------------------------------------------------
__global__ __launch_bounds__(512) void sem_gemm(const float* __restrict__ nf,
                                                const float* __restrict__ wt,
                                                float* __restrict__ att_sem,
                                                float* __restrict__ na_arr) {
  const int bl0 = blockIdx.x * 8;
  const int s = threadIdx.x;
  const float* __restrict__ x0 = nf + (size_t)bl0 * Gs;
  float acc[8];
#pragma unroll
  for (int r = 0; r < 8; ++r) acc[r] = 0.f;
#pragma unroll 4
  for (int t = 0; t < Gs; ++t) {
    const float wv = wt[t * Gs + s];
#pragma unroll
    for (int r = 0; r < 8; ++r) acc[r] = fmaf(wv, x0[r * Gs + t], acc[r]);
  }
#pragma unroll
  for (int r = 0; r < 8; ++r) att_sem[(size_t)(bl0 + r) * Gs + s] = acc[r];

  __shared__ float partial[8][8];
  const int wave = s >> 6, lane = s & 63;
#pragma unroll
  for (int r = 0; r < 8; ++r) {
    float v = acc[r] * acc[r];
#pragma unroll
    for (int off = 32; off > 0; off >>= 1) v += __shfl_xor(v, off);
    if (lane == 0) partial[r][wave] = v;
  }
  __syncthreads();
  if (s < 8) {
    float sum = 0.f;
#pragma unroll
    for (int w2 = 0; w2 < 8; ++w2) sum += partial[s][w2];
    na_arr[bl0 + s] = fmaxf(sqrtf(sum), EPSf);
  }
}

// ---------------------------------------------------------------------------
// Kernel 2: banded semantic attention + softmax. One block per (b,j).
// Writes the FULL output row (zeros outside window) -> serves as out init.
// ---------------------------------------------------------------------------
__global__ __launch_bounds__(256) void sem_attn(const float* __restrict__ nf,
                                                const float* __restrict__ att_sem,
                                                const float* __restrict__ na_arr,
                                                const int* __restrict__ tlen,
                                                float* __restrict__ out) {
  const int blk = blockIdx.x;
  const int b = blk / Ls, j = blk % Ls;
  const int len = tlen[b];
  float* __restrict__ orow = out + (size_t)(b * Ls + j) * MAXNc;
  if (j >= len) {
    for (int k = threadIdx.x; k < MAXNc; k += 256) orow[k] = 0.f;
    return;
  }
  const int k0 = max(j - WPc, 0);
  const int k1 = min(j + WFc, len - 1);
  const int nk = k1 - k0 + 1;   // <= 21

  __shared__ float xs[Gs];
  __shared__ float sc[21];
  __shared__ float red[4];

  const float* __restrict__ x = nf + (size_t)(b * Ls + j) * Gs;
  float ss = 0.f;
  for (int t = threadIdx.x; t < Gs; t += 256) {
    const float v = x[t];
    xs[t] = v;
    ss += v * v;
  }
  const int wave = threadIdx.x >> 6, lane = threadIdx.x & 63;
#pragma unroll
  for (int off = 32; off > 0; off >>= 1) ss += __shfl_xor(ss, off);
  if (lane == 0) red[wave] = ss;
  __syncthreads();
  const float nfn = fmaxf(sqrtf(red[0] + red[1] + red[2] + red[3]), EPSf);

  for (int i = wave; i < nk; i += 4) {
    const int k = k0 + i;
    const float* __restrict__ as = att_sem + (size_t)(b * Ls + k) * Gs;
    float d = 0.f;
#pragma unroll
    for (int t = lane; t < Gs; t += 64) d = fmaf(xs[t], as[t], d);
#pragma unroll
    for (int off = 32; off > 0; off >>= 1) d += __shfl_xor(d, off);
    if (lane == 0) {
      float cs = d / (nfn * na_arr[b * Ls + k]);
      cs = fminf(fmaxf(cs, -CLIPf), CLIPf);
      sc[i] = 1.0f - acosf(cs) * (float)(1.0 / M_PI);
    }
  }
  __syncthreads();
  if (threadIdx.x == 0) {
    float m = -1e30f;
    for (int i = 0; i < nk; ++i) m = fmaxf(m, sc[i]);
    red[0] = m;
  }
  __syncthreads();
  const float m = red[0];
  if ((int)threadIdx.x < nk) sc[threadIdx.x] = expf(sc[threadIdx.x] - m);
  __syncthreads();
  if (threadIdx.x == 0) {
    float s = 0.f;
    for (int i = 0; i < nk; ++i) s += sc[i];
    red[1] = 1.0f / fmaxf(s, EPSf);
  }
  __syncthreads();
  const float inv = red[1];
  for (int k = threadIdx.x; k < MAXNc; k += 256) {
    float v = 0.f;
    if (k >= k0 && k <= k1) v = 0.5f * sc[k - k0] * inv;
    orow[k] = v;
  }
}

// ---------------------------------------------------------------------------
// Kernel 3: flattened MFMA GEMM  Y[Mrows x 300] = K[Mrows x 300] . Wc[300x300]
// then row-normalize (aff/||aff*Y||) and store bf16 ybar (pitch 300).
// Barrier-free main loop: A fragments loaded DIRECTLY from global (two
// float4 per lane, cvt in-flight) -- each wave redundantly covers all 4
// M-tiles (L2 absorbs the 4x; removes all LDS staging + per-chunk barriers
// that produced the round-3 latency wall: MfmaUtil 5.7 / VALU 9.6 / HBM 11%).
// B fragments from zero-padded WcT (no tail masking needed).
// ---------------------------------------------------------------------------
__global__ __launch_bounds__(256) void con_gemm_mfma(const float* __restrict__ kn,
                                                     const short* __restrict__ wct,
                                                     const float* __restrict__ anew,
                                                     const int* __restrict__ tlen,
                                                     unsigned short* __restrict__ ybar) {
  const int row0 = blockIdx.x * 64;
  {
    const int bl0 = row0 / Ns, bl1 = (row0 + 63) / Ns;
    bool alive = false;
    for (int bl = bl0; bl <= bl1; ++bl)
      if ((bl % Ls) < tlen[bl / Ls]) alive = true;
    if (!alive) return;
  }

  __shared__ float rowss[64][4];
  __shared__ float scl[64];

  const int tid = threadIdx.x;
  const int wave = tid >> 6, lane = tid & 63;
  const int quad = lane >> 4, l16 = lane & 15;

  floatx4 acc[4][5];
#pragma unroll
  for (int mt = 0; mt < 4; ++mt)
#pragma unroll
    for (int i = 0; i < 5; ++i) acc[mt][i] = (floatx4){0.f, 0.f, 0.f, 0.f};

  // this lane's A-row base pointers (MFMA A layout: row = l16, k = quad*8+j)
  const float* arow[4];
#pragma unroll
  for (int mt = 0; mt < 4; ++mt)
    arow[mt] = kn + (size_t)(row0 + mt * 16 + l16) * Ds;

  // B row base for this lane's 5 col-tiles
  const short* brow[5];
#pragma unroll
  for (int i = 0; i < 5; ++i)
    brow[i] = wct + (wave * 80 + i * 16 + l16) * 320 + quad * 8;

  // ---- full chunks c = 0..8 (d = 0..287), no masking anywhere
  for (int c = 0; c < 9; ++c) {
    const int d0 = c * 32 + quad * 8;
    short8_t bfrag[5];
#pragma unroll
    for (int i = 0; i < 5; ++i)
      bfrag[i] = *reinterpret_cast<const short8_t*>(brow[i] + c * 32);
#pragma unroll
    for (int mt = 0; mt < 4; ++mt) {
      const float4 v0 = *reinterpret_cast<const float4*>(arow[mt] + d0);
      const float4 v1 = *reinterpret_cast<const float4*>(arow[mt] + d0 + 4);
      const short8_t afrag = cvt8(v0, v1);
#pragma unroll
      for (int i = 0; i < 5; ++i)
        acc[mt][i] = __builtin_amdgcn_mfma_f32_16x16x32_bf16(afrag, bfrag[i], acc[mt][i], 0, 0, 0);
    }
  }

  // ---- tail chunk c = 9 (d = 288..299; A masked per quad, B pad-safe)
  {
    const int d0 = 288 + quad * 8;
    short8_t bfrag[5];
#pragma unroll
    for (int i = 0; i < 5; ++i)
      bfrag[i] = *reinterpret_cast<const short8_t*>(brow[i] + 288);
#pragma unroll
    for (int mt = 0; mt < 4; ++mt) {
      float4 v0 = make_float4(0.f, 0.f, 0.f, 0.f);
      float4 v1 = make_float4(0.f, 0.f, 0.f, 0.f);
      if (quad == 0) {
        v0 = *reinterpret_cast<const float4*>(arow[mt] + d0);
        v1 = *reinterpret_cast<const float4*>(arow[mt] + d0 + 4);
      } else if (quad == 1) {
        v0 = *reinterpret_cast<const float4*>(arow[mt] + d0);   // 296..299
      }
      const short8_t afrag = cvt8(v0, v1);
#pragma unroll
      for (int i = 0; i < 5; ++i)
        acc[mt][i] = __builtin_amdgcn_mfma_f32_16x16x32_bf16(afrag, bfrag[i], acc[mt][i], 0, 0, 0);
    }
  }

  // ---- row sum-of-squares across this wave's 80 cols, cross-wave via LDS
#pragma unroll
  for (int mt = 0; mt < 4; ++mt) {
#pragma unroll
    for (int r = 0; r < 4; ++r) {
      float p = 0.f;
#pragma unroll
      for (int i = 0; i < 5; ++i) {
        const float y = acc[mt][i][r];
        p = fmaf(y, y, p);
      }
      p += __shfl_xor(p, 1);
      p += __shfl_xor(p, 2);
      p += __shfl_xor(p, 4);
      p += __shfl_xor(p, 8);
      if (l16 == 0) rowss[mt * 16 + quad * 4 + r][wave] = p;
    }
  }
  __syncthreads();
  if (tid < 64) {
    const float ss = rowss[tid][0] + rowss[tid][1] + rowss[tid][2] + rowss[tid][3];
    const float a = anew[row0 + tid];
    const float aff = (sqrtf((a - 0.5f) * (a - 0.5f) + 0.25f * a * a) - 0.06467f) *
                      (1.0f / 0.607468f);
    scl[tid] = aff / fmaxf(aff * sqrtf(ss), EPSf);   // aff > 0 always
  }
  __syncthreads();

  // ---- scale + bf16 store (C layout: col = lane&15, row = quad*4+reg)
#pragma unroll
  for (int mt = 0; mt < 4; ++mt) {
#pragma unroll
    for (int i = 0; i < 5; ++i) {
      const int col = wave * 80 + i * 16 + l16;
      if (col < Ds) {
#pragma unroll
        for (int r = 0; r < 4; ++r) {
          const int row = mt * 16 + quad * 4 + r;
          ybar[(size_t)(row0 + row) * Ds + col] = bf16r(acc[mt][i][r] * scl[row]);
        }
      }
    }
  }
}

// ---------------------------------------------------------------------------
// Kernel 4: banded contextual attention via MFMA banded Gram.
// ---------------------------------------------------------------------------
__global__ __launch_bounds__(512) void con_attn_mfma(const float* __restrict__ kn,
                                                     const unsigned short* __restrict__ ybar,
                                                     const int* __restrict__ tlen,
                                                     float* __restrict__ out) {
  const int b = blockIdx.x / 7;
  const int jt = blockIdx.x % 7;
  const int j0 = jt * 16;
  const int len = tlen[b];
  if (j0 >= len) return;                       // rows already zeroed by sem_attn
  const int kbase = min(max(j0 - WPc, 0), Ls - 48);   // 48-window always in-range

  const int tid = threadIdx.x;
  const int wave = tid >> 6, lane = tid & 63;
  const int quad = lane >> 4, l16 = lane & 15;

  __shared__ float red[8][768];   // 24 KB: per-wave partial 16x48 tiles

  const int jj = min(j0 + l16, Ls - 1);        // A-row clamp (tile may overhang L)
  const size_t blj = (size_t)(b * Ls + jj);

  float outacc[3][4];
#pragma unroll
  for (int t = 0; t < 3; ++t)
#pragma unroll
    for (int r = 0; r < 4; ++r) outacc[t][r] = 0.f;

  const unsigned short* yrow[3];
#pragma unroll
  for (int t = 0; t < 3; ++t) {
    const int k = kbase + t * 16 + l16;
    yrow[t] = ybar + ((size_t)(b * Ls + k) * Ns) * Ds;
  }

  for (int ni = 0; ni < 5; ++ni) {
    const int n = wave + ni * 8;
    const float* __restrict__ arow = kn + (blj * Ns + n) * Ds;

    floatx4 S[3];
#pragma unroll
    for (int t = 0; t < 3; ++t) S[t] = (floatx4){0.f, 0.f, 0.f, 0.f};
    float ssq = 0.f;

#pragma unroll
    for (int c = 0; c < 10; ++c) {
      const int d0 = c * 32 + quad * 8;
      float av[8];
      if (c < 9) {
        const float4 v0 = *reinterpret_cast<const float4*>(arow + d0);
        const float4 v1 = *reinterpret_cast<const float4*>(arow + d0 + 4);
        av[0] = v0.x; av[1] = v0.y; av[2] = v0.z; av[3] = v0.w;
        av[4] = v1.x; av[5] = v1.y; av[6] = v1.z; av[7] = v1.w;
      } else {
        if (quad == 0) {
          const float4 v0 = *reinterpret_cast<const float4*>(arow + d0);
          const float4 v1 = *reinterpret_cast<const float4*>(arow + d0 + 4);
          av[0] = v0.x; av[1] = v0.y; av[2] = v0.z; av[3] = v0.w;
          av[4] = v1.x; av[5] = v1.y; av[6] = v1.z; av[7] = v1.w;
        } else if (quad == 1) {
          const float4 v0 = *reinterpret_cast<const float4*>(arow + d0);  // 296..299
          av[0] = v0.x; av[1] = v0.y; av[2] = v0.z; av[3] = v0.w;
          av[4] = av[5] = av[6] = av[7] = 0.f;
        } else {
#pragma unroll
          for (int e = 0; e < 8; ++e) av[e] = 0.f;
        }
      }
      short8_t afrag;
#pragma unroll
      for (int e = 0; e < 8; ++e) {
        ssq = fmaf(av[e], av[e], ssq);
        afrag[e] = (short)bf16r(av[e]);
      }
#pragma unroll
      for (int t = 0; t < 3; ++t) {
        const unsigned short* yr = yrow[t] + (size_t)n * Ds;
        short8_t bfrag;
        if (c < 9) {
          const short4_t u0 = *reinterpret_cast<const short4_t*>(yr + d0);
          const short4_t u1 = *reinterpret_cast<const short4_t*>(yr + d0 + 4);
          bfrag[0] = u0.x; bfrag[1] = u0.y; bfrag[2] = u0.z; bfrag[3] = u0.w;
          bfrag[4] = u1.x; bfrag[5] = u1.y; bfrag[6] = u1.z; bfrag[7] = u1.w;
        } else {
          if (quad == 0) {
            const short4_t u0 = *reinterpret_cast<const short4_t*>(yr + d0);
            const short4_t u1 = *reinterpret_cast<const short4_t*>(yr + d0 + 4);
            bfrag[0] = u0.x; bfrag[1] = u0.y; bfrag[2] = u0.z; bfrag[3] = u0.w;
            bfrag[4] = u1.x; bfrag[5] = u1.y; bfrag[6] = u1.z; bfrag[7] = u1.w;
          } else if (quad == 1) {
            const short4_t u0 = *reinterpret_cast<const short4_t*>(yr + d0);
            bfrag[0] = u0.x; bfrag[1] = u0.y; bfrag[2] = u0.z; bfrag[3] = u0.w;
            bfrag[4] = bfrag[5] = bfrag[6] = bfrag[7] = 0;
          } else {
#pragma unroll
            for (int e = 0; e < 8; ++e) bfrag[e] = 0;
          }
        }
        S[t] = __builtin_amdgcn_mfma_f32_16x16x32_bf16(afrag, bfrag, S[t], 0, 0, 0);
      }
    }

    ssq += __shfl_xor(ssq, 16);
    ssq += __shfl_xor(ssq, 32);
    const float kinv = 1.0f / fmaxf(sqrtf(ssq), EPSf);

#pragma unroll
    for (int r = 0; r < 4; ++r) {
      const float kv = __shfl(kinv, quad * 4 + r);
#pragma unroll
      for (int t = 0; t < 3; ++t)
        outacc[t][r] = fmaf(kv, fabsf(S[t][r]), outacc[t][r]);
    }
  }

#pragma unroll
  for (int t = 0; t < 3; ++t)
#pragma unroll
    for (int r = 0; r < 4; ++r)
      red[wave][(quad * 4 + r) * 48 + t * 16 + l16] = outacc[t][r];
  __syncthreads();

  for (int idx = tid; idx < 768; idx += 512) {
    float s = 0.f;
#pragma unroll
    for (int w = 0; w < 8; ++w) s += red[w][idx];
    const int j = j0 + idx / 48;
    const int k = kbase + idx % 48;
    if (j < len && k < len && k >= j - WPc && k <= j + WFc)
      out[(size_t)(b * Ls + j) * MAXNc + k] += 5.0f * s;   // 0.5 * 10
  }
}

// ---------------------------------------------------------------------------
extern "C" void kernel_launch(void* const* d_in, const int* in_sizes, int n_in,
                              void* d_out, int out_size, void* d_ws, size_t ws_size,
                              hipStream_t stream) {
  const float* nf   = (const float*)d_in[0];   // (B,L,G)
  const float* kn   = (const float*)d_in[1];   // (B,L,N,D)
  const float* anew = (const float*)d_in[2];   // (B,L,N)
  const float* wsem = (const float*)d_in[3];   // (G,G)
  const float* wcon = (const float*)d_in[4];   // (D,D)
  const int*   tlen = (const int*)d_in[5];     // (B,)
  float* out = (float*)d_out;

  // workspace layout (~93 MB)
  float* att_sem = (float*)d_ws;                         // 3520*512 f32
  float* na_arr  = att_sem + (size_t)BL * Gs;            // 3520 f32
  float* wt      = na_arr + BL;                          // 512*512 f32
  short* wct     = (short*)(wt + (size_t)Gs * Gs);       // 320*320 bf16
  unsigned short* ybar = (unsigned short*)(wct + 320 * 320);  // Mrows*300 bf16

  transpose_wsem<<<dim3(16, 16), dim3(32, 8), 0, stream>>>(wsem, wt);
  wct_prep<<<dim3(10, 10), dim3(32, 8), 0, stream>>>(wcon, wct);
  sem_gemm<<<BL / 8, 512, 0, stream>>>(nf, wt, att_sem, na_arr);
  sem_attn<<<BL, 256, 0, stream>>>(nf, att_sem, na_arr, tlen, out);
  con_gemm_mfma<<<Mrows / 64, 256, 0, stream>>>(kn, wct, anew, tlen, ybar);
  con_attn_mfma<<<Bb * 7, 512, 0, stream>>>(kn, ybar, tlen, out);
}

// Round 5
// 513.231 us; speedup vs baseline: 1.0554x; 1.0554x over previous
//
#include <hip/hip_runtime.h>
#include <hip/hip_bf16.h>
#include <math.h>

// Problem constants (from reference)
constexpr int Bb   = 32;
constexpr int Ls   = 110;
constexpr int Gs   = 512;
constexpr int Ns   = 40;
constexpr int Ds   = 300;
constexpr int WPc  = 10;
constexpr int WFc  = 10;
constexpr int MAXNc = 110;
constexpr float EPSf  = 1e-8f;
constexpr float CLIPf = 1.0f - 1e-6f;
constexpr int BL = Bb * Ls;        // 3520
constexpr int Mrows = BL * Ns;     // 140800 flattened GEMM rows
constexpr int BPITCH = 328;        // LDS B pitch in shorts (164 dw == 4 mod 32 -> uniform banks)

typedef __attribute__((ext_vector_type(8))) short short8_t;
typedef __attribute__((ext_vector_type(4))) short short4_t;
typedef __attribute__((ext_vector_type(4))) float floatx4;

__device__ __forceinline__ unsigned short bf16r(float f) {
  unsigned u = __float_as_uint(f);
  u += 0x7fffu + ((u >> 16) & 1u);          // RNE to bf16
  return (unsigned short)(u >> 16);
}

// pack two f32 -> one VGPR holding 2 bf16 (RNE), low = lo
__device__ __forceinline__ unsigned pkbf(float lo, float hi) {
  unsigned a = __float_as_uint(lo), b = __float_as_uint(hi);
  a += 0x7fffu + ((a >> 16) & 1u);
  b += 0x7fffu + ((b >> 16) & 1u);
  return (a >> 16) | (b & 0xffff0000u);
}

__device__ __forceinline__ short8_t cvt8(const float4 v0, const float4 v1) {
  union { short8_t s; unsigned u[4]; } p;
  p.u[0] = pkbf(v0.x, v0.y);
  p.u[1] = pkbf(v0.z, v0.w);
  p.u[2] = pkbf(v1.x, v1.y);
  p.u[3] = pkbf(v1.z, v1.w);
  return p.s;
}

// ---------------------------------------------------------------------------
// Kernel 0: transpose W_sem (512x512) so the sem GEMM reads it coalesced.
// ---------------------------------------------------------------------------
__global__ __launch_bounds__(256) void transpose_wsem(const float* __restrict__ w,
                                                      float* __restrict__ wt) {
  __shared__ float tile[32][33];
  const int bx = blockIdx.x * 32;
  const int by = blockIdx.y * 32;
  const int tx = threadIdx.x;   // 0..31
  const int ty = threadIdx.y;   // 0..7
#pragma unroll
  for (int r = ty; r < 32; r += 8)
    tile[r][tx] = w[(by + r) * Gs + (bx + tx)];
  __syncthreads();
#pragma unroll
  for (int r = ty; r < 32; r += 8)
    wt[(bx + r) * Gs + (by + tx)] = tile[tx][r];   // wt[t][s] = w[s][t]
}

// ---------------------------------------------------------------------------
// Kernel 0b: WcT[t][s] = bf16(Wc[s][t]), zero-padded to [320][320].
// ---------------------------------------------------------------------------
__global__ __launch_bounds__(256) void wct_prep(const float* __restrict__ wc,
                                                short* __restrict__ wct) {
  __shared__ float tile[32][33];
  const int t0 = blockIdx.x * 32;   // t tile
  const int s0 = blockIdx.y * 32;   // s tile
  const int tx = threadIdx.x, ty = threadIdx.y;
#pragma unroll
  for (int r = ty; r < 32; r += 8) {
    const int s = s0 + r, t = t0 + tx;
    tile[r][tx] = (s < Ds && t < Ds) ? wc[s * Ds + t] : 0.f;
  }
  __syncthreads();
#pragma unroll
  for (int r = ty; r < 32; r += 8) {
    const int t = t0 + r, s = s0 + tx;
    wct[t * 320 + s] = (short)bf16r(tile[tx][r]);
  }
}

// ---------------------------------------------------------------------------
// Kernel 1: att_sem[bl,s] = sum_t W[s,t] * x[bl,t]
// ---------------------------------------------------------------------------
__global__ __launch_bounds__(512) void sem_gemm(const float* __restrict__ nf,
                                                const float* __restrict__ wt,
                                                float* __restrict__ att_sem,
                                                float* __restrict__ na_arr) {
  const int bl0 = blockIdx.x * 8;
  const int s = threadIdx.x;
  const float* __restrict__ x0 = nf + (size_t)bl0 * Gs;
  float acc[8];
#pragma unroll
  for (int r = 0; r < 8; ++r) acc[r] = 0.f;
#pragma unroll 4
  for (int t = 0; t < Gs; ++t) {
    const float wv = wt[t * Gs + s];
#pragma unroll
    for (int r = 0; r < 8; ++r) acc[r] = fmaf(wv, x0[r * Gs + t], acc[r]);
  }
#pragma unroll
  for (int r = 0; r < 8; ++r) att_sem[(size_t)(bl0 + r) * Gs + s] = acc[r];

  __shared__ float partial[8][8];
  const int wave = s >> 6, lane = s & 63;
#pragma unroll
  for (int r = 0; r < 8; ++r) {
    float v = acc[r] * acc[r];
#pragma unroll
    for (int off = 32; off > 0; off >>= 1) v += __shfl_xor(v, off);
    if (lane == 0) partial[r][wave] = v;
  }
  __syncthreads();
  if (s < 8) {
    float sum = 0.f;
#pragma unroll
    for (int w2 = 0; w2 < 8; ++w2) sum += partial[s][w2];
    na_arr[bl0 + s] = fmaxf(sqrtf(sum), EPSf);
  }
}

// ---------------------------------------------------------------------------
// Kernel 2: banded semantic attention + softmax. One block per (b,j).
// Writes the FULL output row (zeros outside window) -> serves as out init.
// ---------------------------------------------------------------------------
__global__ __launch_bounds__(256) void sem_attn(const float* __restrict__ nf,
                                                const float* __restrict__ att_sem,
                                                const float* __restrict__ na_arr,
                                                const int* __restrict__ tlen,
                                                float* __restrict__ out) {
  const int blk = blockIdx.x;
  const int b = blk / Ls, j = blk % Ls;
  const int len = tlen[b];
  float* __restrict__ orow = out + (size_t)(b * Ls + j) * MAXNc;
  if (j >= len) {
    for (int k = threadIdx.x; k < MAXNc; k += 256) orow[k] = 0.f;
    return;
  }
  const int k0 = max(j - WPc, 0);
  const int k1 = min(j + WFc, len - 1);
  const int nk = k1 - k0 + 1;   // <= 21

  __shared__ float xs[Gs];
  __shared__ float sc[21];
  __shared__ float red[4];

  const float* __restrict__ x = nf + (size_t)(b * Ls + j) * Gs;
  float ss = 0.f;
  for (int t = threadIdx.x; t < Gs; t += 256) {
    const float v = x[t];
    xs[t] = v;
    ss += v * v;
  }
  const int wave = threadIdx.x >> 6, lane = threadIdx.x & 63;
#pragma unroll
  for (int off = 32; off > 0; off >>= 1) ss += __shfl_xor(ss, off);
  if (lane == 0) red[wave] = ss;
  __syncthreads();
  const float nfn = fmaxf(sqrtf(red[0] + red[1] + red[2] + red[3]), EPSf);

  for (int i = wave; i < nk; i += 4) {
    const int k = k0 + i;
    const float* __restrict__ as = att_sem + (size_t)(b * Ls + k) * Gs;
    float d = 0.f;
#pragma unroll
    for (int t = lane; t < Gs; t += 64) d = fmaf(xs[t], as[t], d);
#pragma unroll
    for (int off = 32; off > 0; off >>= 1) d += __shfl_xor(d, off);
    if (lane == 0) {
      float cs = d / (nfn * na_arr[b * Ls + k]);
      cs = fminf(fmaxf(cs, -CLIPf), CLIPf);
      sc[i] = 1.0f - acosf(cs) * (float)(1.0 / M_PI);
    }
  }
  __syncthreads();
  if (threadIdx.x == 0) {
    float m = -1e30f;
    for (int i = 0; i < nk; ++i) m = fmaxf(m, sc[i]);
    red[0] = m;
  }
  __syncthreads();
  const float m = red[0];
  if ((int)threadIdx.x < nk) sc[threadIdx.x] = expf(sc[threadIdx.x] - m);
  __syncthreads();
  if (threadIdx.x == 0) {
    float s = 0.f;
    for (int i = 0; i < nk; ++i) s += sc[i];
    red[1] = 1.0f / fmaxf(s, EPSf);
  }
  __syncthreads();
  const float inv = red[1];
  for (int k = threadIdx.x; k < MAXNc; k += 256) {
    float v = 0.f;
    if (k >= k0 && k <= k1) v = 0.5f * sc[k - k0] * inv;
    orow[k] = v;
  }
}

// ---------------------------------------------------------------------------
// Kernel 3: flattened MFMA GEMM  Y[Mrows x 300] = K[Mrows x 300] . Wc[300x300]
// N split over blockIdx.y (4 groups x 80 cols) -> per wave: 16 rows x 5 tiles
// (acc = 20 AGPR), A loads 1x per wave with DEPTH-2 prefetch (3-buf rotation),
// B slice (80 cols x 320 k, 52.5 KB) staged once in LDS (single barrier).
// Row-ssq is cross-block now -> partial ssq atomicAdd'd to global rowss[];
// ybar stores UNSCALED bf16(Y); con_attn folds aff/||aff*Y|| per (k,n).
// ---------------------------------------------------------------------------
__global__ __launch_bounds__(256) void con_gemm_mfma(const float* __restrict__ kn,
                                                     const short* __restrict__ wct,
                                                     const int* __restrict__ tlen,
                                                     unsigned short* __restrict__ ybar,
                                                     float* __restrict__ rowss) {
  const int row0 = blockIdx.x * 64;
  {
    const int bl0 = row0 / Ns, bl1 = (row0 + 63) / Ns;
    bool alive = false;
    for (int bl = bl0; bl <= bl1; ++bl)
      if ((bl % Ls) < tlen[bl / Ls]) alive = true;
    if (!alive) return;
  }
  const int n0 = blockIdx.y * 80;

  __shared__ short Bl[80 * BPITCH];   // 52.5 KB

  const int tid = threadIdx.x;
  const int wave = tid >> 6, lane = tid & 63;
  const int quad = lane >> 4, l16 = lane & 15;

  // ---- stage B slice: wct rows n0..n0+79, k = 0..319 (zero-padded source)
  for (int s = tid; s < 80 * 40; s += 256) {
    const int nl = s / 40, slot = s % 40;
    *reinterpret_cast<short8_t*>(&Bl[nl * BPITCH + slot * 8]) =
        *reinterpret_cast<const short8_t*>(wct + (n0 + nl) * 320 + slot * 8);
  }

  const float* __restrict__ arow = kn + (size_t)(row0 + wave * 16 + l16) * Ds;

  floatx4 acc[5];
#pragma unroll
  for (int i = 0; i < 5; ++i) acc[i] = (floatx4){0.f, 0.f, 0.f, 0.f};

  // ---- depth-2 A prefetch (loads are global; independent of the B barrier)
  float4 A0[3], A1[3];
#pragma unroll
  for (int p = 0; p < 2; ++p) {
    const int d0 = p * 32 + quad * 8;
    A0[p] = *reinterpret_cast<const float4*>(arow + d0);
    A1[p] = *reinterpret_cast<const float4*>(arow + d0 + 4);
  }
  __syncthreads();   // B staged

#pragma unroll
  for (int c = 0; c < 10; ++c) {
    // prefetch chunk c+2
    if (c < 8) {
      const int pc = c + 2;
      const int d0 = pc * 32 + quad * 8;
      if (pc < 9) {
        A0[pc % 3] = *reinterpret_cast<const float4*>(arow + d0);
        A1[pc % 3] = *reinterpret_cast<const float4*>(arow + d0 + 4);
      } else {   // tail chunk: valid d 288..299
        float4 v0 = make_float4(0.f, 0.f, 0.f, 0.f);
        float4 v1 = make_float4(0.f, 0.f, 0.f, 0.f);
        if (quad == 0) {
          v0 = *reinterpret_cast<const float4*>(arow + d0);
          v1 = *reinterpret_cast<const float4*>(arow + d0 + 4);
        } else if (quad == 1) {
          v0 = *reinterpret_cast<const float4*>(arow + d0);   // 296..299
        }
        A0[pc % 3] = v0;
        A1[pc % 3] = v1;
      }
    }
    const short8_t afrag = cvt8(A0[c % 3], A1[c % 3]);
#pragma unroll
    for (int i = 0; i < 5; ++i) {
      const short8_t bfrag = *reinterpret_cast<const short8_t*>(
          &Bl[(i * 16 + l16) * BPITCH + c * 32 + quad * 8]);
      acc[i] = __builtin_amdgcn_mfma_f32_16x16x32_bf16(afrag, bfrag, acc[i], 0, 0, 0);
    }
  }

  // ---- partial row-ssq (this block's 80 cols) -> global atomic
  // C layout: col = l16, row = quad*4 + r
#pragma unroll
  for (int r = 0; r < 4; ++r) {
    float p = 0.f;
#pragma unroll
    for (int i = 0; i < 5; ++i) {
      const float y = acc[i][r];
      p = fmaf(y, y, p);
    }
    p += __shfl_xor(p, 1);
    p += __shfl_xor(p, 2);
    p += __shfl_xor(p, 4);
    p += __shfl_xor(p, 8);
    if (l16 == 0)
      atomicAdd(&rowss[row0 + wave * 16 + quad * 4 + r], p);
  }

  // ---- unscaled bf16 store
#pragma unroll
  for (int i = 0; i < 5; ++i) {
    const int col = n0 + i * 16 + l16;
    if (col < Ds) {
#pragma unroll
      for (int r = 0; r < 4; ++r) {
        const int row = row0 + wave * 16 + quad * 4 + r;
        ybar[(size_t)row * Ds + col] = bf16r(acc[i][r]);
      }
    }
  }
}

// ---------------------------------------------------------------------------
// Kernel 4: banded contextual attention via MFMA banded Gram.
// ybar is UNSCALED now; weight w(k,n) = aff(k,n)/max(aff*sqrt(rowss),EPS)
// folded in here (positive -> commutes with abs), kinv(j,n) as before.
// ---------------------------------------------------------------------------
__global__ __launch_bounds__(512) void con_attn_mfma(const float* __restrict__ kn,
                                                     const unsigned short* __restrict__ ybar,
                                                     const float* __restrict__ rowss,
                                                     const float* __restrict__ anew,
                                                     const int* __restrict__ tlen,
                                                     float* __restrict__ out) {
  const int b = blockIdx.x / 7;
  const int jt = blockIdx.x % 7;
  const int j0 = jt * 16;
  const int len = tlen[b];
  if (j0 >= len) return;                       // rows already zeroed by sem_attn
  const int kbase = min(max(j0 - WPc, 0), Ls - 48);   // 48-window always in-range

  const int tid = threadIdx.x;
  const int wave = tid >> 6, lane = tid & 63;
  const int quad = lane >> 4, l16 = lane & 15;

  __shared__ float red[8][768];   // 24 KB: per-wave partial 16x48 tiles

  const int jj = min(j0 + l16, Ls - 1);        // A-row clamp (tile may overhang L)
  const size_t blj = (size_t)(b * Ls + jj);

  float outacc[3][4];
#pragma unroll
  for (int t = 0; t < 3; ++t)
#pragma unroll
    for (int r = 0; r < 4; ++r) outacc[t][r] = 0.f;

  const unsigned short* yrow[3];
  int krow_m[3];    // flattened GEMM row index base for (k, n=0)
#pragma unroll
  for (int t = 0; t < 3; ++t) {
    const int k = kbase + t * 16 + l16;
    yrow[t] = ybar + ((size_t)(b * Ls + k) * Ns) * Ds;
    krow_m[t] = (b * Ls + k) * Ns;
  }

  for (int ni = 0; ni < 5; ++ni) {
    const int n = wave + ni * 8;
    const float* __restrict__ arow = kn + (blj * Ns + n) * Ds;

    // per-(k,n) weight: issue loads early, math is cheap
    float w_t[3];
#pragma unroll
    for (int t = 0; t < 3; ++t) {
      const int m = krow_m[t] + n;
      const float a = anew[m];
      const float ssqk = rowss[m];
      const float aff = (sqrtf((a - 0.5f) * (a - 0.5f) + 0.25f * a * a) - 0.06467f) *
                        (1.0f / 0.607468f);
      w_t[t] = aff / fmaxf(aff * sqrtf(ssqk), EPSf);
    }

    floatx4 S[3];
#pragma unroll
    for (int t = 0; t < 3; ++t) S[t] = (floatx4){0.f, 0.f, 0.f, 0.f};
    float ssq = 0.f;

#pragma unroll
    for (int c = 0; c < 10; ++c) {
      const int d0 = c * 32 + quad * 8;
      float av[8];
      if (c < 9) {
        const float4 v0 = *reinterpret_cast<const float4*>(arow + d0);
        const float4 v1 = *reinterpret_cast<const float4*>(arow + d0 + 4);
        av[0] = v0.x; av[1] = v0.y; av[2] = v0.z; av[3] = v0.w;
        av[4] = v1.x; av[5] = v1.y; av[6] = v1.z; av[7] = v1.w;
      } else {
        if (quad == 0) {
          const float4 v0 = *reinterpret_cast<const float4*>(arow + d0);
          const float4 v1 = *reinterpret_cast<const float4*>(arow + d0 + 4);
          av[0] = v0.x; av[1] = v0.y; av[2] = v0.z; av[3] = v0.w;
          av[4] = v1.x; av[5] = v1.y; av[6] = v1.z; av[7] = v1.w;
        } else if (quad == 1) {
          const float4 v0 = *reinterpret_cast<const float4*>(arow + d0);  // 296..299
          av[0] = v0.x; av[1] = v0.y; av[2] = v0.z; av[3] = v0.w;
          av[4] = av[5] = av[6] = av[7] = 0.f;
        } else {
#pragma unroll
          for (int e = 0; e < 8; ++e) av[e] = 0.f;
        }
      }
      short8_t afrag;
#pragma unroll
      for (int e = 0; e < 8; ++e) {
        ssq = fmaf(av[e], av[e], ssq);
        afrag[e] = (short)bf16r(av[e]);
      }
#pragma unroll
      for (int t = 0; t < 3; ++t) {
        const unsigned short* yr = yrow[t] + (size_t)n * Ds;
        short8_t bfrag;
        if (c < 9) {
          const short4_t u0 = *reinterpret_cast<const short4_t*>(yr + d0);
          const short4_t u1 = *reinterpret_cast<const short4_t*>(yr + d0 + 4);
          bfrag[0] = u0.x; bfrag[1] = u0.y; bfrag[2] = u0.z; bfrag[3] = u0.w;
          bfrag[4] = u1.x; bfrag[5] = u1.y; bfrag[6] = u1.z; bfrag[7] = u1.w;
        } else {
          if (quad == 0) {
            const short4_t u0 = *reinterpret_cast<const short4_t*>(yr + d0);
            const short4_t u1 = *reinterpret_cast<const short4_t*>(yr + d0 + 4);
            bfrag[0] = u0.x; bfrag[1] = u0.y; bfrag[2] = u0.z; bfrag[3] = u0.w;
            bfrag[4] = u1.x; bfrag[5] = u1.y; bfrag[6] = u1.z; bfrag[7] = u1.w;
          } else if (quad == 1) {
            const short4_t u0 = *reinterpret_cast<const short4_t*>(yr + d0);
            bfrag[0] = u0.x; bfrag[1] = u0.y; bfrag[2] = u0.z; bfrag[3] = u0.w;
            bfrag[4] = bfrag[5] = bfrag[6] = bfrag[7] = 0;
          } else {
#pragma unroll
            for (int e = 0; e < 8; ++e) bfrag[e] = 0;
          }
        }
        S[t] = __builtin_amdgcn_mfma_f32_16x16x32_bf16(afrag, bfrag, S[t], 0, 0, 0);
      }
    }

    ssq += __shfl_xor(ssq, 16);
    ssq += __shfl_xor(ssq, 32);
    const float kinv = 1.0f / fmaxf(sqrtf(ssq), EPSf);

#pragma unroll
    for (int r = 0; r < 4; ++r) {
      const float kv = __shfl(kinv, quad * 4 + r);
#pragma unroll
      for (int t = 0; t < 3; ++t)
        outacc[t][r] = fmaf(kv * w_t[t], fabsf(S[t][r]), outacc[t][r]);
    }
  }

#pragma unroll
  for (int t = 0; t < 3; ++t)
#pragma unroll
    for (int r = 0; r < 4; ++r)
      red[wave][(quad * 4 + r) * 48 + t * 16 + l16] = outacc[t][r];
  __syncthreads();

  for (int idx = tid; idx < 768; idx += 512) {
    float s = 0.f;
#pragma unroll
    for (int w = 0; w < 8; ++w) s += red[w][idx];
    const int j = j0 + idx / 48;
    const int k = kbase + idx % 48;
    if (j < len && k < len && k >= j - WPc && k <= j + WFc)
      out[(size_t)(b * Ls + j) * MAXNc + k] += 5.0f * s;   // 0.5 * 10
  }
}

// ---------------------------------------------------------------------------
extern "C" void kernel_launch(void* const* d_in, const int* in_sizes, int n_in,
                              void* d_out, int out_size, void* d_ws, size_t ws_size,
                              hipStream_t stream) {
  const float* nf   = (const float*)d_in[0];   // (B,L,G)
  const float* kn   = (const float*)d_in[1];   // (B,L,N,D)
  const float* anew = (const float*)d_in[2];   // (B,L,N)
  const float* wsem = (const float*)d_in[3];   // (G,G)
  const float* wcon = (const float*)d_in[4];   // (D,D)
  const int*   tlen = (const int*)d_in[5];     // (B,)
  float* out = (float*)d_out;

  // workspace layout (~94 MB)
  float* att_sem = (float*)d_ws;                         // 3520*512 f32
  float* na_arr  = att_sem + (size_t)BL * Gs;            // 3520 f32
  float* wt      = na_arr + BL;                          // 512*512 f32
  short* wct     = (short*)(wt + (size_t)Gs * Gs);       // 320*320 bf16
  float* rowss   = (float*)(wct + 320 * 320);            // Mrows f32
  unsigned short* ybar = (unsigned short*)(rowss + Mrows);  // Mrows*300 bf16

  hipMemsetAsync(rowss, 0, (size_t)Mrows * sizeof(float), stream);
  transpose_wsem<<<dim3(16, 16), dim3(32, 8), 0, stream>>>(wsem, wt);
  wct_prep<<<dim3(10, 10), dim3(32, 8), 0, stream>>>(wcon, wct);
  sem_gemm<<<BL / 8, 512, 0, stream>>>(nf, wt, att_sem, na_arr);
  sem_attn<<<BL, 256, 0, stream>>>(nf, att_sem, na_arr, tlen, out);
  con_gemm_mfma<<<dim3(Mrows / 64, 4), 256, 0, stream>>>(kn, wct, tlen, ybar, rowss);
  con_attn_mfma<<<Bb * 7, 512, 0, stream>>>(kn, ybar, rowss, anew, tlen, out);
}

// Round 6
// 497.048 us; speedup vs baseline: 1.0898x; 1.0326x over previous
//
#include <hip/hip_runtime.h>
#include <hip/hip_bf16.h>
#include <math.h>

// Problem constants (from reference)
constexpr int Bb   = 32;
constexpr int Ls   = 110;
constexpr int Gs   = 512;
constexpr int Ns   = 40;
constexpr int Ds   = 300;
constexpr int WPc  = 10;
constexpr int WFc  = 10;
constexpr int MAXNc = 110;
constexpr float EPSf  = 1e-8f;
constexpr float CLIPf = 1.0f - 1e-6f;
constexpr int BL = Bb * Ls;        // 3520
constexpr int Mrows = BL * Ns;     // 140800 flattened GEMM rows
constexpr int BPITCH = 328;        // LDS B pitch in shorts
constexpr int RGRP = Mrows / 256;  // 550 row-groups of 256

typedef __attribute__((ext_vector_type(8))) short short8_t;
typedef __attribute__((ext_vector_type(4))) short short4_t;
typedef __attribute__((ext_vector_type(4))) float floatx4;

__device__ __forceinline__ unsigned short bf16r(float f) {
  unsigned u = __float_as_uint(f);
  u += 0x7fffu + ((u >> 16) & 1u);          // RNE to bf16
  return (unsigned short)(u >> 16);
}

__device__ __forceinline__ unsigned pkbf(float lo, float hi) {
  unsigned a = __float_as_uint(lo), b = __float_as_uint(hi);
  a += 0x7fffu + ((a >> 16) & 1u);
  b += 0x7fffu + ((b >> 16) & 1u);
  return (a >> 16) | (b & 0xffff0000u);
}

__device__ __forceinline__ short8_t cvt8(const float4 v0, const float4 v1) {
  union { short8_t s; unsigned u[4]; } p;
  p.u[0] = pkbf(v0.x, v0.y);
  p.u[1] = pkbf(v0.z, v0.w);
  p.u[2] = pkbf(v1.x, v1.y);
  p.u[3] = pkbf(v1.z, v1.w);
  return p.s;
}

// ---------------------------------------------------------------------------
// Kernel 0: transpose W_sem (512x512) so the sem GEMM reads it coalesced.
// ---------------------------------------------------------------------------
__global__ __launch_bounds__(256) void transpose_wsem(const float* __restrict__ w,
                                                      float* __restrict__ wt) {
  __shared__ float tile[32][33];
  const int bx = blockIdx.x * 32;
  const int by = blockIdx.y * 32;
  const int tx = threadIdx.x;   // 0..31
  const int ty = threadIdx.y;   // 0..7
#pragma unroll
  for (int r = ty; r < 32; r += 8)
    tile[r][tx] = w[(by + r) * Gs + (bx + tx)];
  __syncthreads();
#pragma unroll
  for (int r = ty; r < 32; r += 8)
    wt[(bx + r) * Gs + (by + tx)] = tile[tx][r];   // wt[t][s] = w[s][t]
}

// ---------------------------------------------------------------------------
// Kernel 0b: WcT[t][s] = bf16(Wc[s][t]), zero-padded to [320][320].
// ---------------------------------------------------------------------------
__global__ __launch_bounds__(256) void wct_prep(const float* __restrict__ wc,
                                                short* __restrict__ wct) {
  __shared__ float tile[32][33];
  const int t0 = blockIdx.x * 32;   // t tile
  const int s0 = blockIdx.y * 32;   // s tile
  const int tx = threadIdx.x, ty = threadIdx.y;
#pragma unroll
  for (int r = ty; r < 32; r += 8) {
    const int s = s0 + r, t = t0 + tx;
    tile[r][tx] = (s < Ds && t < Ds) ? wc[s * Ds + t] : 0.f;
  }
  __syncthreads();
#pragma unroll
  for (int r = ty; r < 32; r += 8) {
    const int t = t0 + r, s = s0 + tx;
    wct[t * 320 + s] = (short)bf16r(tile[tx][r]);
  }
}

// ---------------------------------------------------------------------------
// Kernel 1: att_sem[bl,s] = sum_t W[s,t] * x[bl,t]
// ---------------------------------------------------------------------------
__global__ __launch_bounds__(512) void sem_gemm(const float* __restrict__ nf,
                                                const float* __restrict__ wt,
                                                float* __restrict__ att_sem,
                                                float* __restrict__ na_arr) {
  const int bl0 = blockIdx.x * 8;
  const int s = threadIdx.x;
  const float* __restrict__ x0 = nf + (size_t)bl0 * Gs;
  float acc[8];
#pragma unroll
  for (int r = 0; r < 8; ++r) acc[r] = 0.f;
#pragma unroll 4
  for (int t = 0; t < Gs; ++t) {
    const float wv = wt[t * Gs + s];
#pragma unroll
    for (int r = 0; r < 8; ++r) acc[r] = fmaf(wv, x0[r * Gs + t], acc[r]);
  }
#pragma unroll
  for (int r = 0; r < 8; ++r) att_sem[(size_t)(bl0 + r) * Gs + s] = acc[r];

  __shared__ float partial[8][8];
  const int wave = s >> 6, lane = s & 63;
#pragma unroll
  for (int r = 0; r < 8; ++r) {
    float v = acc[r] * acc[r];
#pragma unroll
    for (int off = 32; off > 0; off >>= 1) v += __shfl_xor(v, off);
    if (lane == 0) partial[r][wave] = v;
  }
  __syncthreads();
  if (s < 8) {
    float sum = 0.f;
#pragma unroll
    for (int w2 = 0; w2 < 8; ++w2) sum += partial[s][w2];
    na_arr[bl0 + s] = fmaxf(sqrtf(sum), EPSf);
  }
}

// ---------------------------------------------------------------------------
// Kernel 2: banded semantic attention + softmax. One block per (b,j).
// Writes the FULL output row (zeros outside window) -> serves as out init.
// ---------------------------------------------------------------------------
__global__ __launch_bounds__(256) void sem_attn(const float* __restrict__ nf,
                                                const float* __restrict__ att_sem,
                                                const float* __restrict__ na_arr,
                                                const int* __restrict__ tlen,
                                                float* __restrict__ out) {
  const int blk = blockIdx.x;
  const int b = blk / Ls, j = blk % Ls;
  const int len = tlen[b];
  float* __restrict__ orow = out + (size_t)(b * Ls + j) * MAXNc;
  if (j >= len) {
    for (int k = threadIdx.x; k < MAXNc; k += 256) orow[k] = 0.f;
    return;
  }
  const int k0 = max(j - WPc, 0);
  const int k1 = min(j + WFc, len - 1);
  const int nk = k1 - k0 + 1;   // <= 21

  __shared__ float xs[Gs];
  __shared__ float sc[21];
  __shared__ float red[4];

  const float* __restrict__ x = nf + (size_t)(b * Ls + j) * Gs;
  float ss = 0.f;
  for (int t = threadIdx.x; t < Gs; t += 256) {
    const float v = x[t];
    xs[t] = v;
    ss += v * v;
  }
  const int wave = threadIdx.x >> 6, lane = threadIdx.x & 63;
#pragma unroll
  for (int off = 32; off > 0; off >>= 1) ss += __shfl_xor(ss, off);
  if (lane == 0) red[wave] = ss;
  __syncthreads();
  const float nfn = fmaxf(sqrtf(red[0] + red[1] + red[2] + red[3]), EPSf);

  for (int i = wave; i < nk; i += 4) {
    const int k = k0 + i;
    const float* __restrict__ as = att_sem + (size_t)(b * Ls + k) * Gs;
    float d = 0.f;
#pragma unroll
    for (int t = lane; t < Gs; t += 64) d = fmaf(xs[t], as[t], d);
#pragma unroll
    for (int off = 32; off > 0; off >>= 1) d += __shfl_xor(d, off);
    if (lane == 0) {
      float cs = d / (nfn * na_arr[b * Ls + k]);
      cs = fminf(fmaxf(cs, -CLIPf), CLIPf);
      sc[i] = 1.0f - acosf(cs) * (float)(1.0 / M_PI);
    }
  }
  __syncthreads();
  if (threadIdx.x == 0) {
    float m = -1e30f;
    for (int i = 0; i < nk; ++i) m = fmaxf(m, sc[i]);
    red[0] = m;
  }
  __syncthreads();
  const float m = red[0];
  if ((int)threadIdx.x < nk) sc[threadIdx.x] = expf(sc[threadIdx.x] - m);
  __syncthreads();
  if (threadIdx.x == 0) {
    float s = 0.f;
    for (int i = 0; i < nk; ++i) s += sc[i];
    red[1] = 1.0f / fmaxf(s, EPSf);
  }
  __syncthreads();
  const float inv = red[1];
  for (int k = threadIdx.x; k < MAXNc; k += 256) {
    float v = 0.f;
    if (k >= k0 && k <= k1) v = 0.5f * sc[k - k0] * inv;
    orow[k] = v;
  }
}

// ---------------------------------------------------------------------------
// Kernel 3: flattened MFMA GEMM  Y[Mrows x 300] = K[Mrows x 300] . Wc[300x300]
// Round-6 structure:
//  - 256 rows/block (wave streams 4 contiguous 16-row tiles) -> B-stage
//    amortized 4x vs r5; single barrier, none in the K-loop.
//  - XCD swizzle: the 4 N-partner blocks (same A rows) map to the SAME XCD
//    (lin%8 round-robin heuristic) -> A HBM-fetched once, partners hit L2.
//  - depth-4 ring prefetch of A chunks per tile; unscaled bf16 store +
//    global rowss atomics (scale folded into con_attn).
// ---------------------------------------------------------------------------
__global__ __launch_bounds__(256, 3) void con_gemm_mfma(const float* __restrict__ kn,
                                                        const short* __restrict__ wct,
                                                        const int* __restrict__ tlen,
                                                        unsigned short* __restrict__ ybar,
                                                        float* __restrict__ rowss) {
  // swizzle decode: xcd = lin%8; partners m=0..3 of group g sit 8 apart
  const int lin = blockIdx.x;
  const int xcd = lin & 7, slot = lin >> 3;
  const int m = slot & 3;
  const int g = xcd + 8 * (slot >> 2);
  if (g >= RGRP) return;
  const int rowbase = g * 256;
  const int n0 = m * 80;

  __shared__ short Bl[80 * BPITCH];   // 52.5 KB
  const int tid = threadIdx.x;
  for (int s = tid; s < 80 * 40; s += 256) {
    const int nl = s / 40, sl = s % 40;
    *reinterpret_cast<short8_t*>(&Bl[nl * BPITCH + sl * 8]) =
        *reinterpret_cast<const short8_t*>(wct + (n0 + nl) * 320 + sl * 8);
  }
  __syncthreads();   // the only barrier

  const int wave = tid >> 6, lane = tid & 63;
  const int quad = lane >> 4, l16 = lane & 15;

#pragma unroll
  for (int tt = 0; tt < 4; ++tt) {
    const int row0 = rowbase + wave * 64 + tt * 16;
    const int blA = row0 / Ns, blB = (row0 + 15) / Ns;
    const bool alive = ((blA % Ls) < tlen[blA / Ls]) | ((blB % Ls) < tlen[blB / Ls]);
    if (!alive) continue;   // wave-uniform, no barriers in loop

    const float* __restrict__ arow = kn + (size_t)(row0 + l16) * Ds;

    // ring-4 A prefetch (chunks 0..3 are all full: d < 288)
    float4 A0[4], A1[4];
#pragma unroll
    for (int p = 0; p < 4; ++p) {
      const int d0 = p * 32 + quad * 8;
      A0[p] = *reinterpret_cast<const float4*>(arow + d0);
      A1[p] = *reinterpret_cast<const float4*>(arow + d0 + 4);
    }

    floatx4 acc[5];
#pragma unroll
    for (int i = 0; i < 5; ++i) acc[i] = (floatx4){0.f, 0.f, 0.f, 0.f};

#pragma unroll
    for (int c = 0; c < 10; ++c) {
      const short8_t afrag = cvt8(A0[c & 3], A1[c & 3]);   // consume buffer
      const int pc = c + 4;                                 // refill same slot
      if (pc < 9) {
        const int d0 = pc * 32 + quad * 8;
        A0[c & 3] = *reinterpret_cast<const float4*>(arow + d0);
        A1[c & 3] = *reinterpret_cast<const float4*>(arow + d0 + 4);
      } else if (pc == 9) {       // tail chunk: valid d 288..299
        const int d0 = 288 + quad * 8;
        float4 v0 = make_float4(0.f, 0.f, 0.f, 0.f);
        float4 v1 = make_float4(0.f, 0.f, 0.f, 0.f);
        if (quad == 0) {
          v0 = *reinterpret_cast<const float4*>(arow + d0);
          v1 = *reinterpret_cast<const float4*>(arow + d0 + 4);
        } else if (quad == 1) {
          v0 = *reinterpret_cast<const float4*>(arow + d0);   // 296..299
        }
        A0[c & 3] = v0;
        A1[c & 3] = v1;
      }
#pragma unroll
      for (int i = 0; i < 5; ++i) {
        const short8_t bfrag = *reinterpret_cast<const short8_t*>(
            &Bl[(i * 16 + l16) * BPITCH + c * 32 + quad * 8]);
        acc[i] = __builtin_amdgcn_mfma_f32_16x16x32_bf16(afrag, bfrag, acc[i], 0, 0, 0);
      }
    }

    // epilogue: partial row-ssq -> global atomic; unscaled bf16 store
    // C layout: col = l16 (+16i), row = quad*4 + r
#pragma unroll
    for (int r = 0; r < 4; ++r) {
      float p = 0.f;
#pragma unroll
      for (int i = 0; i < 5; ++i) p = fmaf(acc[i][r], acc[i][r], p);
      p += __shfl_xor(p, 1);
      p += __shfl_xor(p, 2);
      p += __shfl_xor(p, 4);
      p += __shfl_xor(p, 8);
      if (l16 == 0) atomicAdd(&rowss[row0 + quad * 4 + r], p);
    }
#pragma unroll
    for (int i = 0; i < 5; ++i) {
      const int col = n0 + i * 16 + l16;
      if (col < Ds) {
#pragma unroll
        for (int r = 0; r < 4; ++r)
          ybar[(size_t)(row0 + quad * 4 + r) * Ds + col] = bf16r(acc[i][r]);
      }
    }
  }
}

// ---------------------------------------------------------------------------
// Kernel 4: banded contextual attention via MFMA banded Gram.
// ybar is UNSCALED; weight w(k,n) = aff(k,n)/max(aff*sqrt(rowss),EPS)
// folded in here (positive -> commutes with abs), kinv(j,n) as before.
// ---------------------------------------------------------------------------
__global__ __launch_bounds__(512) void con_attn_mfma(const float* __restrict__ kn,
                                                     const unsigned short* __restrict__ ybar,
                                                     const float* __restrict__ rowss,
                                                     const float* __restrict__ anew,
                                                     const int* __restrict__ tlen,
                                                     float* __restrict__ out) {
  const int b = blockIdx.x / 7;
  const int jt = blockIdx.x % 7;
  const int j0 = jt * 16;
  const int len = tlen[b];
  if (j0 >= len) return;                       // rows already zeroed by sem_attn
  const int kbase = min(max(j0 - WPc, 0), Ls - 48);   // 48-window always in-range

  const int tid = threadIdx.x;
  const int wave = tid >> 6, lane = tid & 63;
  const int quad = lane >> 4, l16 = lane & 15;

  __shared__ float red[8][768];   // 24 KB: per-wave partial 16x48 tiles

  const int jj = min(j0 + l16, Ls - 1);        // A-row clamp (tile may overhang L)
  const size_t blj = (size_t)(b * Ls + jj);

  float outacc[3][4];
#pragma unroll
  for (int t = 0; t < 3; ++t)
#pragma unroll
    for (int r = 0; r < 4; ++r) outacc[t][r] = 0.f;

  const unsigned short* yrow[3];
  int krow_m[3];    // flattened GEMM row index base for (k, n=0)
#pragma unroll
  for (int t = 0; t < 3; ++t) {
    const int k = kbase + t * 16 + l16;
    yrow[t] = ybar + ((size_t)(b * Ls + k) * Ns) * Ds;
    krow_m[t] = (b * Ls + k) * Ns;
  }

  for (int ni = 0; ni < 5; ++ni) {
    const int n = wave + ni * 8;
    const float* __restrict__ arow = kn + (blj * Ns + n) * Ds;

    // per-(k,n) weight: issue loads early, math is cheap
    float w_t[3];
#pragma unroll
    for (int t = 0; t < 3; ++t) {
      const int mm = krow_m[t] + n;
      const float a = anew[mm];
      const float ssqk = rowss[mm];
      const float aff = (sqrtf((a - 0.5f) * (a - 0.5f) + 0.25f * a * a) - 0.06467f) *
                        (1.0f / 0.607468f);
      w_t[t] = aff / fmaxf(aff * sqrtf(ssqk), EPSf);
    }

    floatx4 S[3];
#pragma unroll
    for (int t = 0; t < 3; ++t) S[t] = (floatx4){0.f, 0.f, 0.f, 0.f};
    float ssq = 0.f;

#pragma unroll
    for (int c = 0; c < 10; ++c) {
      const int d0 = c * 32 + quad * 8;
      float av[8];
      if (c < 9) {
        const float4 v0 = *reinterpret_cast<const float4*>(arow + d0);
        const float4 v1 = *reinterpret_cast<const float4*>(arow + d0 + 4);
        av[0] = v0.x; av[1] = v0.y; av[2] = v0.z; av[3] = v0.w;
        av[4] = v1.x; av[5] = v1.y; av[6] = v1.z; av[7] = v1.w;
      } else {
        if (quad == 0) {
          const float4 v0 = *reinterpret_cast<const float4*>(arow + d0);
          const float4 v1 = *reinterpret_cast<const float4*>(arow + d0 + 4);
          av[0] = v0.x; av[1] = v0.y; av[2] = v0.z; av[3] = v0.w;
          av[4] = v1.x; av[5] = v1.y; av[6] = v1.z; av[7] = v1.w;
        } else if (quad == 1) {
          const float4 v0 = *reinterpret_cast<const float4*>(arow + d0);  // 296..299
          av[0] = v0.x; av[1] = v0.y; av[2] = v0.z; av[3] = v0.w;
          av[4] = av[5] = av[6] = av[7] = 0.f;
        } else {
#pragma unroll
          for (int e = 0; e < 8; ++e) av[e] = 0.f;
        }
      }
      short8_t afrag;
#pragma unroll
      for (int e = 0; e < 8; ++e) {
        ssq = fmaf(av[e], av[e], ssq);
        afrag[e] = (short)bf16r(av[e]);
      }
#pragma unroll
      for (int t = 0; t < 3; ++t) {
        const unsigned short* yr = yrow[t] + (size_t)n * Ds;
        short8_t bfrag;
        if (c < 9) {
          const short4_t u0 = *reinterpret_cast<const short4_t*>(yr + d0);
          const short4_t u1 = *reinterpret_cast<const short4_t*>(yr + d0 + 4);
          bfrag[0] = u0.x; bfrag[1] = u0.y; bfrag[2] = u0.z; bfrag[3] = u0.w;
          bfrag[4] = u1.x; bfrag[5] = u1.y; bfrag[6] = u1.z; bfrag[7] = u1.w;
        } else {
          if (quad == 0) {
            const short4_t u0 = *reinterpret_cast<const short4_t*>(yr + d0);
            const short4_t u1 = *reinterpret_cast<const short4_t*>(yr + d0 + 4);
            bfrag[0] = u0.x; bfrag[1] = u0.y; bfrag[2] = u0.z; bfrag[3] = u0.w;
            bfrag[4] = u1.x; bfrag[5] = u1.y; bfrag[6] = u1.z; bfrag[7] = u1.w;
          } else if (quad == 1) {
            const short4_t u0 = *reinterpret_cast<const short4_t*>(yr + d0);
            bfrag[0] = u0.x; bfrag[1] = u0.y; bfrag[2] = u0.z; bfrag[3] = u0.w;
            bfrag[4] = bfrag[5] = bfrag[6] = bfrag[7] = 0;
          } else {
#pragma unroll
            for (int e = 0; e < 8; ++e) bfrag[e] = 0;
          }
        }
        S[t] = __builtin_amdgcn_mfma_f32_16x16x32_bf16(afrag, bfrag, S[t], 0, 0, 0);
      }
    }

    ssq += __shfl_xor(ssq, 16);
    ssq += __shfl_xor(ssq, 32);
    const float kinv = 1.0f / fmaxf(sqrtf(ssq), EPSf);

#pragma unroll
    for (int r = 0; r < 4; ++r) {
      const float kv = __shfl(kinv, quad * 4 + r);
#pragma unroll
      for (int t = 0; t < 3; ++t)
        outacc[t][r] = fmaf(kv * w_t[t], fabsf(S[t][r]), outacc[t][r]);
    }
  }

#pragma unroll
  for (int t = 0; t < 3; ++t)
#pragma unroll
    for (int r = 0; r < 4; ++r)
      red[wave][(quad * 4 + r) * 48 + t * 16 + l16] = outacc[t][r];
  __syncthreads();

  for (int idx = tid; idx < 768; idx += 512) {
    float s = 0.f;
#pragma unroll
    for (int w = 0; w < 8; ++w) s += red[w][idx];
    const int j = j0 + idx / 48;
    const int k = kbase + idx % 48;
    if (j < len && k < len && k >= j - WPc && k <= j + WFc)
      out[(size_t)(b * Ls + j) * MAXNc + k] += 5.0f * s;   // 0.5 * 10
  }
}

// ---------------------------------------------------------------------------
extern "C" void kernel_launch(void* const* d_in, const int* in_sizes, int n_in,
                              void* d_out, int out_size, void* d_ws, size_t ws_size,
                              hipStream_t stream) {
  const float* nf   = (const float*)d_in[0];   // (B,L,G)
  const float* kn   = (const float*)d_in[1];   // (B,L,N,D)
  const float* anew = (const float*)d_in[2];   // (B,L,N)
  const float* wsem = (const float*)d_in[3];   // (G,G)
  const float* wcon = (const float*)d_in[4];   // (D,D)
  const int*   tlen = (const int*)d_in[5];     // (B,)
  float* out = (float*)d_out;

  // workspace layout (~94 MB)
  float* att_sem = (float*)d_ws;                         // 3520*512 f32
  float* na_arr  = att_sem + (size_t)BL * Gs;            // 3520 f32
  float* wt      = na_arr + BL;                          // 512*512 f32
  short* wct     = (short*)(wt + (size_t)Gs * Gs);       // 320*320 bf16
  float* rowss   = (float*)(wct + 320 * 320);            // Mrows f32
  unsigned short* ybar = (unsigned short*)(rowss + Mrows);  // Mrows*300 bf16

  hipMemsetAsync(rowss, 0, (size_t)Mrows * sizeof(float), stream);
  transpose_wsem<<<dim3(16, 16), dim3(32, 8), 0, stream>>>(wsem, wt);
  wct_prep<<<dim3(10, 10), dim3(32, 8), 0, stream>>>(wcon, wct);
  sem_gemm<<<BL / 8, 512, 0, stream>>>(nf, wt, att_sem, na_arr);
  sem_attn<<<BL, 256, 0, stream>>>(nf, att_sem, na_arr, tlen, out);
  // 2208 = 8 XCDs * 276 slots; g-guard trims the 2 spare groups
  con_gemm_mfma<<<2208, 256, 0, stream>>>(kn, wct, tlen, ybar, rowss);
  con_attn_mfma<<<Bb * 7, 512, 0, stream>>>(kn, ybar, rowss, anew, tlen, out);
}